// Round 10
// baseline (489.186 us; speedup 1.0000x reference)
//
#include <hip/hip_runtime.h>

#define HD 128
#define NCOPY 32
#define BSH 8
#define BSZ 256
#define EPB 4096

typedef __attribute__((ext_vector_type(8))) short short8;
typedef __attribute__((ext_vector_type(4))) float f32x4;

union ABu { unsigned long long u[2]; short8 s8; };

__device__ inline float bf2f(ushort u) {
    union { unsigned int i; float f; } x; x.i = ((unsigned int)u) << 16; return x.f;
}
__device__ inline float bflo(unsigned int u) {
    union { unsigned int i; float f; } x; x.i = u << 16; return x.f;
}
__device__ inline float bfhi(unsigned int u) {
    union { unsigned int i; float f; } x; x.i = u & 0xffff0000u; return x.f;
}
__device__ inline ushort f2bf(float f) {
    union { float f; unsigned int i; } x; x.f = f;
    unsigned int r = x.i + 0x7FFF + ((x.i >> 16) & 1);
    return (ushort)(r >> 16);
}

// ---------------- prep (x->bf16, W transpose->bf16) + bucket count, block-split --------
__global__ __launch_bounds__(256) void k_prepcount(
        const float* __restrict__ x, ushort* __restrict__ xb, int total4,
        const float* __restrict__ Wl, const float* __restrict__ Wr,
        ushort* __restrict__ WT, int wtTotal,
        const int* __restrict__ dst, int* __restrict__ bucketCount, int E, int NB, int nPB) {
    __shared__ int hist[512];
    if (blockIdx.x < nPB) {
        for (int i = threadIdx.x; i < NB; i += 256) hist[i] = 0;
        __syncthreads();
        int e0 = blockIdx.x * EPB;
#pragma unroll
        for (int j = 0; j < 16; ++j) {
            int e = e0 + j * 256 + threadIdx.x;
            if (e < E) atomicAdd(&hist[dst[e] >> BSH], 1);
        }
        __syncthreads();
        for (int i = threadIdx.x; i < NB; i += 256)
            if (hist[i]) atomicAdd(&bucketCount[i], hist[i]);
    } else {
        int i = (blockIdx.x - nPB) * 256 + threadIdx.x;
        int stride = (gridDim.x - nPB) * 256;
        for (int idx = i; idx < total4; idx += stride) {
            float4 v = ((const float4*)x)[idx];
            ushort4 o;
            o.x = f2bf(v.x); o.y = f2bf(v.y); o.z = f2bf(v.z); o.w = f2bf(v.w);
            ((ushort4*)xb)[idx] = o;
        }
        for (int idx = i; idx < wtTotal; idx += stride) {
            int l = idx >> 15;
            int rem = idx & 32767;
            int col = rem >> 8;
            int k = rem & 255;
            float v = (k < 128) ? Wl[l * 16384 + k * 128 + col]
                                : Wr[l * 16384 + (k - 128) * 128 + col];
            WT[idx] = f2bf(v);
        }
    }
}

// ---------------- partition: computes bucket bases internally (scan of bCount) ---------
__global__ __launch_bounds__(256) void kp_part(const int* __restrict__ src,
                                               const int* __restrict__ dst,
                                               const int* __restrict__ bCount,
                                               int* __restrict__ gCursor,
                                               unsigned int* __restrict__ packed,
                                               int E, int NB) {
    __shared__ int bbase[512];
    __shared__ int pair[256];
    __shared__ int hist[512], lbase[512], lcur[512];
    int tid = threadIdx.x;
    int i0 = 2 * tid, i1 = 2 * tid + 1;
    int v0 = (i0 < NB) ? bCount[i0] : 0;
    int v1 = (i1 < NB) ? bCount[i1] : 0;
    pair[tid] = v0 + v1;
    __syncthreads();
    for (int off = 1; off < 256; off <<= 1) {
        int t = 0;
        if (tid >= off) t = pair[tid - off];
        __syncthreads();
        if (tid >= off) pair[tid] += t;
        __syncthreads();
    }
    int incl = pair[tid];
    bbase[i0] = incl - v0 - v1;
    bbase[i1] = incl - v1;
    for (int i = tid; i < NB; i += 256) hist[i] = 0;
    __syncthreads();

    int e0 = blockIdx.x * EPB;
    int b[16]; unsigned int w[16];
#pragma unroll
    for (int j = 0; j < 16; ++j) {
        int e = e0 + j * 256 + tid;
        b[j] = -1;
        if (e < E) {
            int d = dst[e];
            int s = src[e];
            b[j] = d >> BSH;
            w[j] = (unsigned int)s | (((unsigned int)d & (BSZ - 1)) << 17);
            atomicAdd(&hist[b[j]], 1);
        }
    }
    __syncthreads();
    for (int i = tid; i < NB; i += 256) {
        int c = hist[i];
        lbase[i] = c ? (bbase[i] + atomicAdd(&gCursor[i], c)) : 0;
        lcur[i] = 0;
    }
    __syncthreads();
#pragma unroll
    for (int j = 0; j < 16; ++j) {
        if (b[j] >= 0) {
            int r = atomicAdd(&lcur[b[j]], 1);
            packed[lbase[b[j]] + r] = w[j];
        }
    }
}

// ---------------- degfill: bucket base via internal reduction; rowptr/inv/csr ----------
__global__ __launch_bounds__(256) void kp_degfill(const unsigned int* __restrict__ packed,
                                                  const int* __restrict__ bCount,
                                                  int* __restrict__ rowptr,
                                                  float* __restrict__ inv,
                                                  int* __restrict__ csr, int N, int E, int NB) {
    __shared__ int dcnt[BSZ];
    __shared__ int scn[BSZ];
    __shared__ int rp[BSZ];
    __shared__ int red[256];
    int bkt = blockIdx.x;
    int tid = threadIdx.x;
    int n0 = bkt << BSH;
    int partial = 0;
    for (int i = tid; i < bkt; i += 256) partial += bCount[i];
    red[tid] = partial;
    __syncthreads();
    for (int off = 128; off > 0; off >>= 1) {
        if (tid < off) red[tid] += red[tid + off];
        __syncthreads();
    }
    int beg = red[0];
    int end = beg + bCount[bkt];
    __syncthreads();
    dcnt[tid] = 0;
    __syncthreads();
    for (int e = beg + tid; e < end; e += 256)
        atomicAdd(&dcnt[packed[e] >> 17], 1);
    __syncthreads();
    int v = dcnt[tid];
    scn[tid] = v;
    __syncthreads();
    for (int off = 1; off < 256; off <<= 1) {
        int t = 0;
        if (tid >= off) t = scn[tid - off];
        __syncthreads();
        if (tid >= off) scn[tid] += t;
        __syncthreads();
    }
    int rpv = beg + scn[tid] - v;
    int n = n0 + tid;
    if (n < N) {
        rowptr[n] = rpv;
        inv[n] = (v > 0) ? (1.0f / (float)v) : 0.0f;
    }
    if (bkt == 0 && tid == 0) rowptr[N] = E;
    __syncthreads();
    dcnt[tid] = 0;
    rp[tid] = rpv;
    __syncthreads();
    for (int e = beg + tid; e < end; e += 256) {
        unsigned int wv = packed[e];
        int ld = wv >> 17;
        int p = atomicAdd(&dcnt[ld], 1);
        csr[rp[ld] + p] = (int)(wv & 0x1FFFF);
    }
}

// ---------------- PASS 1 (merged): gemm blocks [0,gg2) compute out=h@Wr+bias;
//                  agg blocks [gg2, gg2+agrid) compute aggb=mean gather of h. ----------
// gemm part: 64x128 tile, 4 waves (2x2), K=128 in 4 chunks of 32. LDS ~15.4KB, lean VGPR.
__global__ __launch_bounds__(256) void k_aggemm(
        const ushort* __restrict__ h, const int* __restrict__ rowptr,
        const int* __restrict__ csr, const float* __restrict__ inv,
        ushort* __restrict__ aggb,
        const ushort* __restrict__ WT, const float* __restrict__ bias,
        ushort* __restrict__ out, int N, int gg2) {
    __shared__ ushort As[64 * 40];    // 5 KB
    __shared__ ushort Bs[128 * 40];   // 10 KB
    int tid = threadIdx.x;
    if ((int)blockIdx.x < gg2) {
        int lane = tid & 63, wid = tid >> 6;
        int wr = wid >> 1, wc = wid & 1;
        int ln15 = lane & 15, kg = lane >> 4;
        int rbase = blockIdx.x * 64;
        f32x4 acc[2][4];
#pragma unroll
        for (int m = 0; m < 2; ++m)
#pragma unroll
            for (int nn = 0; nn < 4; ++nn) acc[m][nn] = (f32x4){0.f, 0.f, 0.f, 0.f};
        int rA = tid >> 2, qA = (tid & 3) * 8;
        for (int c = 0; c < 4; ++c) {
            int cb = c * 32;
            // A: 64 rows x 32 k
            {
                int grow = rbase + rA;
                uint4 v = {0u, 0u, 0u, 0u};
                if (grow < N) v = *(const uint4*)&h[(size_t)grow * HD + cb + qA];
                *(uint4*)&As[rA * 40 + qA] = v;
            }
            // B: 128 cols x 32 k (Wr half: +128 in WT's k)
#pragma unroll
            for (int p = 0; p < 2; ++p) {
                int g = tid + p * 256;
                int col = g >> 2, q = (g & 3) * 8;
                *(uint4*)&Bs[col * 40 + q] = *(const uint4*)&WT[col * 256 + 128 + cb + q];
            }
            __syncthreads();
            short8 af[2], bfr[4];
#pragma unroll
            for (int m = 0; m < 2; ++m) {
                int row = wr * 32 + m * 16 + ln15;
                const ushort* pa = &As[row * 40 + kg * 4];
                ABu u; u.u[0] = *(const unsigned long long*)pa;
                u.u[1] = *(const unsigned long long*)(pa + 16);
                af[m] = u.s8;
            }
#pragma unroll
            for (int nn = 0; nn < 4; ++nn) {
                int col = wc * 64 + nn * 16 + ln15;
                const ushort* pb = &Bs[col * 40 + kg * 4];
                ABu u; u.u[0] = *(const unsigned long long*)pb;
                u.u[1] = *(const unsigned long long*)(pb + 16);
                bfr[nn] = u.s8;
            }
#pragma unroll
            for (int m = 0; m < 2; ++m)
#pragma unroll
                for (int nn = 0; nn < 4; ++nn)
                    acc[m][nn] = __builtin_amdgcn_mfma_f32_16x16x32_bf16(af[m], bfr[nn], acc[m][nn], 0, 0, 0);
            __syncthreads();
        }
        float bv[4];
#pragma unroll
        for (int nn = 0; nn < 4; ++nn) bv[nn] = bias[wc * 64 + nn * 16 + ln15];
#pragma unroll
        for (int m = 0; m < 2; ++m) {
#pragma unroll
            for (int j = 0; j < 4; ++j) {
                int row = rbase + wr * 32 + m * 16 + kg * 4 + j;
                if (row < N) {
#pragma unroll
                    for (int nn = 0; nn < 4; ++nn)
                        out[(size_t)row * HD + wc * 64 + nn * 16 + ln15] = f2bf(acc[m][nn][j] + bv[nn]);
                }
            }
        }
    } else {
        // aggregation: one wave per node, 8 rows in flight (R5-proven body)
        int node = ((int)blockIdx.x - gg2) * 4 + (tid >> 6);
        if (node >= N) return;
        int lane = tid & 63;
        int g = lane >> 4, ln = lane & 15;
        int beg = rowptr[node], end = rowptr[node + 1];
        float a[8], b[8];
#pragma unroll
        for (int j = 0; j < 8; ++j) { a[j] = 0.f; b[j] = 0.f; }
        for (int e = beg + g; e < end; e += 8) {
            int s0 = csr[e];
            uint4 v0 = *(const uint4*)&h[(size_t)s0 * HD + ln * 8];
            int e1 = e + 4;
            if (e1 < end) {
                int s1 = csr[e1];
                uint4 v1 = *(const uint4*)&h[(size_t)s1 * HD + ln * 8];
                b[0] += bflo(v1.x); b[1] += bfhi(v1.x);
                b[2] += bflo(v1.y); b[3] += bfhi(v1.y);
                b[4] += bflo(v1.z); b[5] += bfhi(v1.z);
                b[6] += bflo(v1.w); b[7] += bfhi(v1.w);
            }
            a[0] += bflo(v0.x); a[1] += bfhi(v0.x);
            a[2] += bflo(v0.y); a[3] += bfhi(v0.y);
            a[4] += bflo(v0.z); a[5] += bfhi(v0.z);
            a[6] += bflo(v0.w); a[7] += bfhi(v0.w);
        }
#pragma unroll
        for (int j = 0; j < 8; ++j) {
            a[j] += b[j];
            a[j] += __shfl_xor(a[j], 16);
            a[j] += __shfl_xor(a[j], 32);
        }
        if (lane < 16) {
            float iv = inv[node];
            ushort o[8];
#pragma unroll
            for (int j = 0; j < 8; ++j) o[j] = f2bf(a[j] * iv);
            *(uint4*)&aggb[(size_t)node * HD + ln * 8] = *(uint4*)o;
        }
    }
}

// ---------------- PASS 2: out += aggb@Wl (K=128), stats in epilogue ----------------
// 128x128 tile, 4 waves (2x2), 2 chunks of BK=64 (R7-proven staging shape).
__global__ __launch_bounds__(256) void k_gemmWl(
        const ushort* __restrict__ X, const ushort* __restrict__ WT,
        ushort* __restrict__ out, float* __restrict__ stats, int N) {
    __shared__ ushort As[128 * 72];
    __shared__ ushort Bs[128 * 72];
    int tid = threadIdx.x;
    int lane = tid & 63, wid = tid >> 6;
    int wr = wid >> 1, wc = wid & 1;
    int ln15 = lane & 15, kg = lane >> 4;
    int rbase = blockIdx.x * 128;

    f32x4 acc[4][4];
#pragma unroll
    for (int m = 0; m < 4; ++m)
#pragma unroll
        for (int nn = 0; nn < 4; ++nn) acc[m][nn] = (f32x4){0.f, 0.f, 0.f, 0.f};

    for (int c = 0; c < 2; ++c) {
        int cb = c * 64;
#pragma unroll
        for (int p = 0; p < 4; ++p) {
            int g = tid + p * 256;
            int r = g >> 3, q = g & 7;
            int grow = rbase + r;
            uint4 v = {0u, 0u, 0u, 0u};
            if (grow < N) v = *(const uint4*)&X[(size_t)grow * HD + cb + q * 8];
            *(uint4*)&As[r * 72 + q * 8] = v;
        }
#pragma unroll
        for (int p = 0; p < 4; ++p) {
            int g = tid + p * 256;
            int col = g >> 3, q = g & 7;
            *(uint4*)&Bs[col * 72 + q * 8] = *(const uint4*)&WT[col * 256 + cb + q * 8];
        }
        __syncthreads();
#pragma unroll
        for (int kk = 0; kk < 2; ++kk) {
            short8 af[4], bfr[4];
#pragma unroll
            for (int m = 0; m < 4; ++m) {
                int row = wr * 64 + m * 16 + ln15;
                const ushort* pa = &As[row * 72 + kk * 32 + kg * 4];
                ABu u; u.u[0] = *(const unsigned long long*)pa;
                u.u[1] = *(const unsigned long long*)(pa + 16);
                af[m] = u.s8;
            }
#pragma unroll
            for (int nn = 0; nn < 4; ++nn) {
                int col = wc * 64 + nn * 16 + ln15;
                const ushort* pb = &Bs[col * 72 + kk * 32 + kg * 4];
                ABu u; u.u[0] = *(const unsigned long long*)pb;
                u.u[1] = *(const unsigned long long*)(pb + 16);
                bfr[nn] = u.s8;
            }
#pragma unroll
            for (int m = 0; m < 4; ++m)
#pragma unroll
                for (int nn = 0; nn < 4; ++nn)
                    acc[m][nn] = __builtin_amdgcn_mfma_f32_16x16x32_bf16(af[m], bfr[nn], acc[m][nn], 0, 0, 0);
        }
        __syncthreads();
    }

    float s[4] = {0.f, 0.f, 0.f, 0.f};
    float q[4] = {0.f, 0.f, 0.f, 0.f};
#pragma unroll
    for (int m = 0; m < 4; ++m) {
#pragma unroll
        for (int j = 0; j < 4; ++j) {
            int row = rbase + wr * 64 + m * 16 + kg * 4 + j;
            if (row < N) {
#pragma unroll
                for (int nn = 0; nn < 4; ++nn) {
                    size_t oidx = (size_t)row * HD + wc * 64 + nn * 16 + ln15;
                    float v = acc[m][nn][j] + bf2f(out[oidx]);
                    out[oidx] = f2bf(v);
                    s[nn] += v; q[nn] += v * v;
                }
            }
        }
    }
#pragma unroll
    for (int nn = 0; nn < 4; ++nn) {
        s[nn] += __shfl_xor(s[nn], 16); s[nn] += __shfl_xor(s[nn], 32);
        q[nn] += __shfl_xor(q[nn], 16); q[nn] += __shfl_xor(q[nn], 32);
    }
    if (lane < 16) {
        int slot = (blockIdx.x & (NCOPY - 1)) * 256;
#pragma unroll
        for (int nn = 0; nn < 4; ++nn) {
            int col = wc * 64 + nn * 16 + lane;
            atomicAdd(&stats[slot + col], s[nn]);
            atomicAdd(&stats[slot + 128 + col], q[nn]);
        }
    }
}

// ---------------- BN finalize folded + apply + LeakyReLU, IN-PLACE ----------------
__global__ __launch_bounds__(256) void k_apply(ushort* buf, const float* __restrict__ stats,
                                               const float* __restrict__ gamma,
                                               const float* __restrict__ beta,
                                               float count, int total8) {
    __shared__ float sc[HD], sh[HD];
    int tid = threadIdx.x;
    if (tid < HD) {
        float s = 0.f, q = 0.f;
        for (int i = 0; i < NCOPY; ++i) { s += stats[i * 256 + tid]; q += stats[i * 256 + 128 + tid]; }
        float mean = s / count;
        float var = fmaxf(q / count - mean * mean, 0.f);
        float scale = gamma[tid] * rsqrtf(var + 1e-5f);
        sc[tid] = scale;
        sh[tid] = beta[tid] - mean * scale;
    }
    __syncthreads();
    int i = blockIdx.x * blockDim.x + tid;
    int stride = gridDim.x * blockDim.x;
    for (int idx = i; idx < total8; idx += stride) {
        int cb = (idx * 8) & (HD - 1);
        uint4 v = ((const uint4*)buf)[idx];
        float f[8];
        f[0] = bflo(v.x); f[1] = bfhi(v.x);
        f[2] = bflo(v.y); f[3] = bfhi(v.y);
        f[4] = bflo(v.z); f[5] = bfhi(v.z);
        f[6] = bflo(v.w); f[7] = bfhi(v.w);
        ushort o[8];
#pragma unroll
        for (int j = 0; j < 8; ++j) {
            float y = f[j] * sc[cb + j] + sh[cb + j];
            y = (y > 0.f) ? y : 0.2f * y;
            o[j] = f2bf(y);
        }
        ((uint4*)buf)[idx] = *(uint4*)o;
    }
}

// ---------------- Pooling, 64 nodes/block, fused BN finalize+apply ----------------
__global__ void k_poolapply(const ushort* __restrict__ h, const float* __restrict__ stats,
                            const float* __restrict__ gamma, const float* __restrict__ beta,
                            float count, const int* __restrict__ batch,
                            float* __restrict__ pooled, int N) {
    int c = threadIdx.x;  // 128
    float s = 0.f, q = 0.f;
    for (int i = 0; i < NCOPY; ++i) { s += stats[i * 256 + c]; q += stats[i * 256 + 128 + c]; }
    float mean = s / count;
    float var = fmaxf(q / count - mean * mean, 0.f);
    float sc = gamma[c] * rsqrtf(var + 1e-5f);
    float sh = beta[c] - mean * sc;
    int n0 = blockIdx.x * 64;
    if (n0 >= N) return;
    int nend = min(n0 + 64, N);
    float acc = 0.f;
    int cur = batch[n0];
    for (int n = n0; n < nend; ++n) {
        int b = batch[n];
        if (b != cur) { atomicAdd(&pooled[cur * HD + c], acc); acc = 0.f; cur = b; }
        float y = bf2f(h[(size_t)n * HD + c]) * sc + sh;
        y = (y > 0.f) ? y : 0.2f * y;
        acc += y;
    }
    atomicAdd(&pooled[cur * HD + c], acc);
}

// ---------------- column stats over pooled [rows][128] ----------------
__global__ void k_colstats(const float* __restrict__ X, float* __restrict__ stats, int rows) {
    int c = threadIdx.x;  // 128
    float s = 0.f, q = 0.f;
    for (int r = blockIdx.x; r < rows; r += gridDim.x) {
        float v = X[r * HD + c];
        s += v; q += v * v;
    }
    int slot = (blockIdx.x & (NCOPY - 1)) * 256;
    atomicAdd(&stats[slot + c], s);
    atomicAdd(&stats[slot + 128 + c], q);
}

// ---------------- final: BN2 finalize folded; out[g] = bn2(pooled[g]) @ fcW + fcb ------
__global__ void k_final(const float* __restrict__ pooled, const float* __restrict__ stats2,
                        const float* __restrict__ bn2g, const float* __restrict__ bn2b,
                        const float* __restrict__ fcW, const float* __restrict__ fcb,
                        float* __restrict__ outp, float countG) {
    __shared__ float Wlds[HD * 64];
    __shared__ float prow[HD];
    int tid = threadIdx.x;  // 128
    for (int i = tid; i < HD * 64 / 4; i += 128) ((float4*)Wlds)[i] = ((const float4*)fcW)[i];
    float s = 0.f, q = 0.f;
    for (int i = 0; i < NCOPY; ++i) { s += stats2[i * 256 + tid]; q += stats2[i * 256 + 128 + tid]; }
    float mean = s / countG;
    float var = fmaxf(q / countG - mean * mean, 0.f);
    float scale = bn2g[tid] * rsqrtf(var + 1e-5f);
    float shift = bn2b[tid] - mean * scale;
    int g = blockIdx.x;
    prow[tid] = pooled[g * HD + tid] * scale + shift;
    __syncthreads();
    if (tid < 64) {
        float acc = fcb[tid];
#pragma unroll 8
        for (int c = 0; c < HD; ++c) acc += prow[c] * Wlds[c * 64 + tid];
        outp[g * 64 + tid] = acc;
    }
}

// ---------------- host orchestration ----------------
extern "C" void kernel_launch(void* const* d_in, const int* in_sizes, int n_in,
                              void* d_out, int out_size, void* d_ws, size_t ws_size,
                              hipStream_t stream) {
    const float* x     = (const float*)d_in[0];
    const int*   ei    = (const int*)d_in[1];
    const int*   batch = (const int*)d_in[2];
    const float* Wl    = (const float*)d_in[3];
    const float* bl    = (const float*)d_in[4];
    const float* Wr    = (const float*)d_in[5];
    const float* bng   = (const float*)d_in[6];
    const float* bnb   = (const float*)d_in[7];
    const float* bn2g  = (const float*)d_in[8];
    const float* bn2b  = (const float*)d_in[9];
    const float* fcW   = (const float*)d_in[10];
    const float* fcb   = (const float*)d_in[11];

    int N = in_sizes[0] / HD;
    int E = in_sizes[1] / 2;
    int G = out_size / 64;
    const int* src = ei;
    const int* dst = ei + E;

    char* p = (char*)d_ws;
    auto alloc = [&](size_t bytes) -> void* {
        void* r = (void*)p;
        p += (bytes + 255) & ~(size_t)255;
        return r;
    };
    int NB = (N + BSZ - 1) >> BSH;
    int nPB = (E + EPB - 1) / EPB;

    int*    rowptr   = (int*)alloc((size_t)(N + 1) * 4);
    int*    csr      = (int*)alloc((size_t)E * 4);
    float*  inv      = (float*)alloc((size_t)N * 4);
    ushort* WT       = (ushort*)alloc((size_t)3 * 128 * 256 * 2);
    ushort* xb       = (ushort*)alloc((size_t)N * HD * 2);
    ushort* aggb     = (ushort*)alloc((size_t)N * HD * 2);
    ushort* hb1      = (ushort*)alloc((size_t)N * HD * 2);
    ushort* hb2      = (ushort*)alloc((size_t)N * HD * 2);
    char*   zbase    = (char*)alloc(0);
    float*  statsAll = (float*)alloc((size_t)4 * NCOPY * 256 * 4);
    float*  pooled   = (float*)alloc((size_t)G * HD * 4);
    int*    bCount   = (int*)alloc((size_t)NB * 4);
    int*    gCursor  = (int*)alloc((size_t)NB * 4);
    size_t  zbytes   = (size_t)((char*)p - zbase);

    float* stats0  = statsAll;
    float* stats1  = statsAll + NCOPY * 256;
    float* statsL2 = statsAll + 2 * NCOPY * 256;
    float* stats2  = statsAll + 3 * NCOPY * 256;

    // packed edge list overlays aggb: dead before first pass-1 writes aggb (stream-ordered)
    unsigned int* packed = (unsigned int*)aggb;

    float* outp = (float*)d_out;
    int total4 = N * HD / 4;
    int total8 = N * HD / 8;
    int gg2   = (N + 63) / 64;     // pass-1 gemm blocks (64-row tiles)
    int ggrid = (N + 127) / 128;   // pass-2 gemm blocks
    int agrid = (N + 3) / 4;       // agg blocks
    float fN = (float)N, fG = (float)G;

    hipMemsetAsync(zbase, 0, zbytes, stream);
    k_prepcount<<<nPB + 1024, 256, 0, stream>>>(x, xb, total4, Wl, Wr, WT, 3 * 128 * 256,
                                                dst, bCount, E, NB, nPB);
    kp_part<<<nPB, 256, 0, stream>>>(src, dst, bCount, gCursor, packed, E, NB);
    kp_degfill<<<NB, 256, 0, stream>>>(packed, bCount, rowptr, inv, csr, N, E, NB);

    // layer 0: h=xb -> hb1
    k_aggemm<<<gg2 + agrid, 256, 0, stream>>>(xb, rowptr, csr, inv, aggb, WT, bl, hb1, N, gg2);
    k_gemmWl<<<ggrid, 256, 0, stream>>>(aggb, WT, hb1, stats0, N);
    k_apply<<<2048, 256, 0, stream>>>(hb1, stats0, bng, bnb, fN, total8);

    // layer 1: h=hb1 -> hb2
    k_aggemm<<<gg2 + agrid, 256, 0, stream>>>(hb1, rowptr, csr, inv, aggb, WT + 32768, bl + 128, hb2, N, gg2);
    k_gemmWl<<<ggrid, 256, 0, stream>>>(aggb, WT + 32768, hb2, stats1, N);
    k_apply<<<2048, 256, 0, stream>>>(hb2, stats1, bng + 128, bnb + 128, fN, total8);

    // layer 2: h=hb2 -> hb1 (pre-BN); BN finalize+apply fused into pooling
    k_aggemm<<<gg2 + agrid, 256, 0, stream>>>(hb2, rowptr, csr, inv, aggb, WT + 65536, bl + 256, hb1, N, gg2);
    k_gemmWl<<<ggrid, 256, 0, stream>>>(aggb, WT + 65536, hb1, statsL2, N);
    k_poolapply<<<(N + 63) / 64, HD, 0, stream>>>(hb1, statsL2, bng + 256, bnb + 256, fN,
                                                  batch, pooled, N);

    // final BN + FC
    k_colstats<<<64, HD, 0, stream>>>(pooled, stats2, G);
    k_final<<<G, HD, 0, stream>>>(pooled, stats2, bn2g, bn2b, fcW, fcb, outp, fG);
}

// Round 11
// 381.499 us; speedup vs baseline: 1.2823x; 1.2823x over previous
//
#include <hip/hip_runtime.h>

#define HD 128
#define NCOPY 32
#define BSH 8
#define BSZ 256
#define EPB 4096

typedef __attribute__((ext_vector_type(8))) short short8;
typedef __attribute__((ext_vector_type(4))) float f32x4;

union ABu { unsigned long long u[2]; short8 s8; };

typedef const __attribute__((address_space(1))) void* gas_t;
typedef __attribute__((address_space(3))) void* las_t;

__device__ inline float bf2f(ushort u) {
    union { unsigned int i; float f; } x; x.i = ((unsigned int)u) << 16; return x.f;
}
__device__ inline float bflo(unsigned int u) {
    union { unsigned int i; float f; } x; x.i = u << 16; return x.f;
}
__device__ inline float bfhi(unsigned int u) {
    union { unsigned int i; float f; } x; x.i = u & 0xffff0000u; return x.f;
}
__device__ inline ushort f2bf(float f) {
    union { float f; unsigned int i; } x; x.f = f;
    unsigned int r = x.i + 0x7FFF + ((x.i >> 16) & 1);
    return (ushort)(r >> 16);
}

// XOR-swizzled fragment read from linear [*][64-ushort] tile (rows 128B apart).
// LDS[row][sb] holds global block (sb ^ (row&7)); reading block b uses sb = b ^ (row&7).
__device__ inline short8 frag_read(const ushort* tile, int row, int kk, int kg) {
    const char* rowp = (const char*)(tile + row * 64);
    int sw = (row & 7) << 4;
    int b0 = kk * 64 + kg * 8;
    int a0 = (b0 & 15) | ((b0 & ~15) ^ sw);
    int b1 = b0 + 32;
    int a1 = (b1 & 15) | ((b1 & ~15) ^ sw);
    ABu u;
    u.u[0] = *(const unsigned long long*)(rowp + a0);
    u.u[1] = *(const unsigned long long*)(rowp + a1);
    return u.s8;
}

// ---------------- prep (x->bf16, WTS swizzled-transpose->bf16) + bucket count ----------
// WTS layout (per layer, 32768 ushorts): [chunk c:4][col:128][sb:8][j:8] where the
// stored element is W[k = c*64 + (sb^(col&7))*8 + j][col]; k<128 -> Wl, else Wr.
__global__ __launch_bounds__(256) void k_prepcount(
        const float* __restrict__ x, ushort* __restrict__ xb, int total4,
        const float* __restrict__ Wl, const float* __restrict__ Wr,
        ushort* __restrict__ WTS, int wtTotal,
        const int* __restrict__ dst, int* __restrict__ bucketCount, int E, int NB, int nPB) {
    __shared__ int hist[512];
    if (blockIdx.x < nPB) {
        for (int i = threadIdx.x; i < NB; i += 256) hist[i] = 0;
        __syncthreads();
        int e0 = blockIdx.x * EPB;
#pragma unroll
        for (int j = 0; j < 16; ++j) {
            int e = e0 + j * 256 + threadIdx.x;
            if (e < E) atomicAdd(&hist[dst[e] >> BSH], 1);
        }
        __syncthreads();
        for (int i = threadIdx.x; i < NB; i += 256)
            if (hist[i]) atomicAdd(&bucketCount[i], hist[i]);
    } else {
        int i = (blockIdx.x - nPB) * 256 + threadIdx.x;
        int stride = (gridDim.x - nPB) * 256;
        for (int idx = i; idx < total4; idx += stride) {
            float4 v = ((const float4*)x)[idx];
            ushort4 o;
            o.x = f2bf(v.x); o.y = f2bf(v.y); o.z = f2bf(v.z); o.w = f2bf(v.w);
            ((ushort4*)xb)[idx] = o;
        }
        for (int idx = i; idx < wtTotal; idx += stride) {
            int l = idx >> 15;
            int r = idx & 32767;
            int c = r >> 13;
            int r2 = r & 8191;
            int col = r2 >> 6;
            int kin = r2 & 63;
            int sb = kin >> 3, j = kin & 7;
            int b = sb ^ (col & 7);
            int k = c * 64 + b * 8 + j;
            float v = (k < 128) ? Wl[l * 16384 + k * 128 + col]
                                : Wr[l * 16384 + (k - 128) * 128 + col];
            WTS[idx] = f2bf(v);
        }
    }
}

// ---------------- partition: computes bucket bases internally (scan of bCount) ---------
__global__ __launch_bounds__(256) void kp_part(const int* __restrict__ src,
                                               const int* __restrict__ dst,
                                               const int* __restrict__ bCount,
                                               int* __restrict__ gCursor,
                                               unsigned int* __restrict__ packed,
                                               int E, int NB) {
    __shared__ int bbase[512];
    __shared__ int pair[256];
    __shared__ int hist[512], lbase[512], lcur[512];
    int tid = threadIdx.x;
    int i0 = 2 * tid, i1 = 2 * tid + 1;
    int v0 = (i0 < NB) ? bCount[i0] : 0;
    int v1 = (i1 < NB) ? bCount[i1] : 0;
    pair[tid] = v0 + v1;
    __syncthreads();
    for (int off = 1; off < 256; off <<= 1) {
        int t = 0;
        if (tid >= off) t = pair[tid - off];
        __syncthreads();
        if (tid >= off) pair[tid] += t;
        __syncthreads();
    }
    int incl = pair[tid];
    bbase[i0] = incl - v0 - v1;
    bbase[i1] = incl - v1;
    for (int i = tid; i < NB; i += 256) hist[i] = 0;
    __syncthreads();

    int e0 = blockIdx.x * EPB;
    int b[16]; unsigned int w[16];
#pragma unroll
    for (int j = 0; j < 16; ++j) {
        int e = e0 + j * 256 + tid;
        b[j] = -1;
        if (e < E) {
            int d = dst[e];
            int s = src[e];
            b[j] = d >> BSH;
            w[j] = (unsigned int)s | (((unsigned int)d & (BSZ - 1)) << 17);
            atomicAdd(&hist[b[j]], 1);
        }
    }
    __syncthreads();
    for (int i = tid; i < NB; i += 256) {
        int c = hist[i];
        lbase[i] = c ? (bbase[i] + atomicAdd(&gCursor[i], c)) : 0;
        lcur[i] = 0;
    }
    __syncthreads();
#pragma unroll
    for (int j = 0; j < 16; ++j) {
        if (b[j] >= 0) {
            int r = atomicAdd(&lcur[b[j]], 1);
            packed[lbase[b[j]] + r] = w[j];
        }
    }
}

// ---------------- degfill: bucket base via internal reduction; rowptr/inv/csr ----------
__global__ __launch_bounds__(256) void kp_degfill(const unsigned int* __restrict__ packed,
                                                  const int* __restrict__ bCount,
                                                  int* __restrict__ rowptr,
                                                  float* __restrict__ inv,
                                                  int* __restrict__ csr, int N, int E, int NB) {
    __shared__ int dcnt[BSZ];
    __shared__ int scn[BSZ];
    __shared__ int rp[BSZ];
    __shared__ int red[256];
    int bkt = blockIdx.x;
    int tid = threadIdx.x;
    int n0 = bkt << BSH;
    int partial = 0;
    for (int i = tid; i < bkt; i += 256) partial += bCount[i];
    red[tid] = partial;
    __syncthreads();
    for (int off = 128; off > 0; off >>= 1) {
        if (tid < off) red[tid] += red[tid + off];
        __syncthreads();
    }
    int beg = red[0];
    int end = beg + bCount[bkt];
    __syncthreads();
    dcnt[tid] = 0;
    __syncthreads();
    for (int e = beg + tid; e < end; e += 256)
        atomicAdd(&dcnt[packed[e] >> 17], 1);
    __syncthreads();
    int v = dcnt[tid];
    scn[tid] = v;
    __syncthreads();
    for (int off = 1; off < 256; off <<= 1) {
        int t = 0;
        if (tid >= off) t = scn[tid - off];
        __syncthreads();
        if (tid >= off) scn[tid] += t;
        __syncthreads();
    }
    int rpv = beg + scn[tid] - v;
    int n = n0 + tid;
    if (n < N) {
        rowptr[n] = rpv;
        inv[n] = (v > 0) ? (1.0f / (float)v) : 0.0f;
    }
    if (bkt == 0 && tid == 0) rowptr[N] = E;
    __syncthreads();
    dcnt[tid] = 0;
    rp[tid] = rpv;
    __syncthreads();
    for (int e = beg + tid; e < end; e += 256) {
        unsigned int wv = packed[e];
        int ld = wv >> 17;
        int p = atomicAdd(&dcnt[ld], 1);
        csr[rp[ld] + p] = (int)(wv & 0x1FFFF);
    }
}

// ---------------- Aggregation: one wave per node, 8 rows in flight (R5-proven) ----------------
__global__ __launch_bounds__(256) void k_agg(const ushort* __restrict__ h,
                                             const int* __restrict__ rowptr,
                                             const int* __restrict__ csr,
                                             const float* __restrict__ inv,
                                             ushort* __restrict__ agg, int N) {
    int node = blockIdx.x * 4 + (threadIdx.x >> 6);
    if (node >= N) return;
    int lane = threadIdx.x & 63;
    int g = lane >> 4, ln = lane & 15;
    int beg = rowptr[node], end = rowptr[node + 1];
    float a[8], b[8];
#pragma unroll
    for (int j = 0; j < 8; ++j) { a[j] = 0.f; b[j] = 0.f; }
    for (int e = beg + g; e < end; e += 8) {
        int s0 = csr[e];
        uint4 v0 = *(const uint4*)&h[(size_t)s0 * HD + ln * 8];
        int e1 = e + 4;
        if (e1 < end) {
            int s1 = csr[e1];
            uint4 v1 = *(const uint4*)&h[(size_t)s1 * HD + ln * 8];
            b[0] += bflo(v1.x); b[1] += bfhi(v1.x);
            b[2] += bflo(v1.y); b[3] += bfhi(v1.y);
            b[4] += bflo(v1.z); b[5] += bfhi(v1.z);
            b[6] += bflo(v1.w); b[7] += bfhi(v1.w);
        }
        a[0] += bflo(v0.x); a[1] += bfhi(v0.x);
        a[2] += bflo(v0.y); a[3] += bfhi(v0.y);
        a[4] += bflo(v0.z); a[5] += bfhi(v0.z);
        a[6] += bflo(v0.w); a[7] += bfhi(v0.w);
    }
#pragma unroll
    for (int j = 0; j < 8; ++j) {
        a[j] += b[j];
        a[j] += __shfl_xor(a[j], 16);
        a[j] += __shfl_xor(a[j], 32);
    }
    if (lane < 16) {
        float iv = inv[node];
        ushort o[8];
#pragma unroll
        for (int j = 0; j < 8; ++j) o[j] = f2bf(a[j] * iv);
        *(uint4*)&agg[(size_t)node * HD + ln * 8] = *(uint4*)o;
    }
}

// ---------------- MFMA dual-GEMM, BK=64, global_load_lds staging ----------------
// 128x128 tile, 4 waves (2x2), K=256 in 4 chunks of 64 (chunks 0-1: X1@Wl; 2-3: X2@Wr).
// A: linear LDS [128][64], per-lane source block XOR-swizzled (sb^(row&7)); B: WTS is
// pre-swizzled chunk-major so staging is a contiguous 1KB/wave copy. Reads via frag_read.
__global__ __launch_bounds__(256) void k_gemm(
        const ushort* __restrict__ X1, const ushort* __restrict__ X2,
        const ushort* __restrict__ WTS, const float* __restrict__ bias,
        ushort* __restrict__ out, float* __restrict__ stats, int N) {
    __shared__ ushort As[128 * 64];   // 16 KB
    __shared__ ushort Bs[128 * 64];   // 16 KB
    int tid = threadIdx.x;
    int lane = tid & 63, wid = tid >> 6;
    int wr = wid >> 1, wc = wid & 1;
    int ln15 = lane & 15, kg = lane >> 4;
    int rbase = blockIdx.x * 128;
    int lrow = lane >> 3;     // 0..7 within instruction
    int sb = lane & 7;        // block 0..7

    f32x4 acc[4][4];
#pragma unroll
    for (int m = 0; m < 4; ++m)
#pragma unroll
        for (int nn = 0; nn < 4; ++nn) acc[m][nn] = (f32x4){0.f, 0.f, 0.f, 0.f};

    for (int c = 0; c < 4; ++c) {
        const ushort* X = (c < 2) ? X1 : X2;
        size_t cbyte = (size_t)(c & 1) * 128;   // byte offset within X row
        const char* bsrc = (const char*)WTS + (size_t)c * 16384;
#pragma unroll
        for (int p = 0; p < 4; ++p) {
            int instr = wid * 4 + p;                 // 0..15
            int row_local = instr * 8 + lrow;
            int grow = rbase + row_local;
            if (grow >= N) grow = N - 1;             // rows >= N never stored
            const char* gpA = (const char*)X + (size_t)grow * 256 + cbyte
                              + (((sb ^ (row_local & 7)) << 4));
            __builtin_amdgcn_global_load_lds((gas_t)gpA,
                    (las_t)((char*)As + instr * 1024), 16, 0, 0);
            const char* gpB = bsrc + instr * 1024 + lane * 16;
            __builtin_amdgcn_global_load_lds((gas_t)gpB,
                    (las_t)((char*)Bs + instr * 1024), 16, 0, 0);
        }
        __syncthreads();
#pragma unroll
        for (int kk = 0; kk < 2; ++kk) {
            short8 af[4], bfr[4];
#pragma unroll
            for (int m = 0; m < 4; ++m)
                af[m] = frag_read(As, wr * 64 + m * 16 + ln15, kk, kg);
#pragma unroll
            for (int nn = 0; nn < 4; ++nn)
                bfr[nn] = frag_read(Bs, wc * 64 + nn * 16 + ln15, kk, kg);
#pragma unroll
            for (int m = 0; m < 4; ++m)
#pragma unroll
                for (int nn = 0; nn < 4; ++nn)
                    acc[m][nn] = __builtin_amdgcn_mfma_f32_16x16x32_bf16(af[m], bfr[nn], acc[m][nn], 0, 0, 0);
        }
        __syncthreads();
    }

    float s[4] = {0.f, 0.f, 0.f, 0.f};
    float q[4] = {0.f, 0.f, 0.f, 0.f};
    float bv[4];
#pragma unroll
    for (int nn = 0; nn < 4; ++nn) bv[nn] = bias[wc * 64 + nn * 16 + ln15];
#pragma unroll
    for (int m = 0; m < 4; ++m) {
#pragma unroll
        for (int j = 0; j < 4; ++j) {
            int row = rbase + wr * 64 + m * 16 + kg * 4 + j;
            if (row < N) {
#pragma unroll
                for (int nn = 0; nn < 4; ++nn) {
                    float v = acc[m][nn][j] + bv[nn];
                    out[(size_t)row * HD + wc * 64 + nn * 16 + ln15] = f2bf(v);
                    s[nn] += v; q[nn] += v * v;
                }
            }
        }
    }
#pragma unroll
    for (int nn = 0; nn < 4; ++nn) {
        s[nn] += __shfl_xor(s[nn], 16); s[nn] += __shfl_xor(s[nn], 32);
        q[nn] += __shfl_xor(q[nn], 16); q[nn] += __shfl_xor(q[nn], 32);
    }
    if (lane < 16) {
        int slot = (blockIdx.x & (NCOPY - 1)) * 256;
#pragma unroll
        for (int nn = 0; nn < 4; ++nn) {
            int col = wc * 64 + nn * 16 + lane;
            atomicAdd(&stats[slot + col], s[nn]);
            atomicAdd(&stats[slot + 128 + col], q[nn]);
        }
    }
}

// ---------------- BN finalize folded + apply + LeakyReLU, IN-PLACE ----------------
__global__ __launch_bounds__(256) void k_apply(ushort* buf, const float* __restrict__ stats,
                                               const float* __restrict__ gamma,
                                               const float* __restrict__ beta,
                                               float count, int total8) {
    __shared__ float sc[HD], sh[HD];
    int tid = threadIdx.x;
    if (tid < HD) {
        float s = 0.f, q = 0.f;
        for (int i = 0; i < NCOPY; ++i) { s += stats[i * 256 + tid]; q += stats[i * 256 + 128 + tid]; }
        float mean = s / count;
        float var = fmaxf(q / count - mean * mean, 0.f);
        float scale = gamma[tid] * rsqrtf(var + 1e-5f);
        sc[tid] = scale;
        sh[tid] = beta[tid] - mean * scale;
    }
    __syncthreads();
    int i = blockIdx.x * blockDim.x + tid;
    int stride = gridDim.x * blockDim.x;
    for (int idx = i; idx < total8; idx += stride) {
        int cb = (idx * 8) & (HD - 1);
        uint4 v = ((const uint4*)buf)[idx];
        float f[8];
        f[0] = bflo(v.x); f[1] = bfhi(v.x);
        f[2] = bflo(v.y); f[3] = bfhi(v.y);
        f[4] = bflo(v.z); f[5] = bfhi(v.z);
        f[6] = bflo(v.w); f[7] = bfhi(v.w);
        ushort o[8];
#pragma unroll
        for (int j = 0; j < 8; ++j) {
            float y = f[j] * sc[cb + j] + sh[cb + j];
            y = (y > 0.f) ? y : 0.2f * y;
            o[j] = f2bf(y);
        }
        ((uint4*)buf)[idx] = *(uint4*)o;
    }
}

// ---------------- Pooling, 64 nodes/block, fused BN finalize+apply ----------------
__global__ void k_poolapply(const ushort* __restrict__ h, const float* __restrict__ stats,
                            const float* __restrict__ gamma, const float* __restrict__ beta,
                            float count, const int* __restrict__ batch,
                            float* __restrict__ pooled, int N) {
    int c = threadIdx.x;  // 128
    float s = 0.f, q = 0.f;
    for (int i = 0; i < NCOPY; ++i) { s += stats[i * 256 + c]; q += stats[i * 256 + 128 + c]; }
    float mean = s / count;
    float var = fmaxf(q / count - mean * mean, 0.f);
    float sc = gamma[c] * rsqrtf(var + 1e-5f);
    float sh = beta[c] - mean * sc;
    int n0 = blockIdx.x * 64;
    if (n0 >= N) return;
    int nend = min(n0 + 64, N);
    float acc = 0.f;
    int cur = batch[n0];
    for (int n = n0; n < nend; ++n) {
        int b = batch[n];
        if (b != cur) { atomicAdd(&pooled[cur * HD + c], acc); acc = 0.f; cur = b; }
        float y = bf2f(h[(size_t)n * HD + c]) * sc + sh;
        y = (y > 0.f) ? y : 0.2f * y;
        acc += y;
    }
    atomicAdd(&pooled[cur * HD + c], acc);
}

// ---------------- column stats over pooled [rows][128] ----------------
__global__ void k_colstats(const float* __restrict__ X, float* __restrict__ stats, int rows) {
    int c = threadIdx.x;  // 128
    float s = 0.f, q = 0.f;
    for (int r = blockIdx.x; r < rows; r += gridDim.x) {
        float v = X[r * HD + c];
        s += v; q += v * v;
    }
    int slot = (blockIdx.x & (NCOPY - 1)) * 256;
    atomicAdd(&stats[slot + c], s);
    atomicAdd(&stats[slot + 128 + c], q);
}

// ---------------- final: BN2 finalize folded; out[g] = bn2(pooled[g]) @ fcW + fcb ------
__global__ void k_final(const float* __restrict__ pooled, const float* __restrict__ stats2,
                        const float* __restrict__ bn2g, const float* __restrict__ bn2b,
                        const float* __restrict__ fcW, const float* __restrict__ fcb,
                        float* __restrict__ outp, float countG) {
    __shared__ float Wlds[HD * 64];
    __shared__ float prow[HD];
    int tid = threadIdx.x;  // 128
    for (int i = tid; i < HD * 64 / 4; i += 128) ((float4*)Wlds)[i] = ((const float4*)fcW)[i];
    float s = 0.f, q = 0.f;
    for (int i = 0; i < NCOPY; ++i) { s += stats2[i * 256 + tid]; q += stats2[i * 256 + 128 + tid]; }
    float mean = s / countG;
    float var = fmaxf(q / countG - mean * mean, 0.f);
    float scale = bn2g[tid] * rsqrtf(var + 1e-5f);
    float shift = bn2b[tid] - mean * scale;
    int g = blockIdx.x;
    prow[tid] = pooled[g * HD + tid] * scale + shift;
    __syncthreads();
    if (tid < 64) {
        float acc = fcb[tid];
#pragma unroll 8
        for (int c = 0; c < HD; ++c) acc += prow[c] * Wlds[c * 64 + tid];
        outp[g * 64 + tid] = acc;
    }
}

// ---------------- host orchestration ----------------
extern "C" void kernel_launch(void* const* d_in, const int* in_sizes, int n_in,
                              void* d_out, int out_size, void* d_ws, size_t ws_size,
                              hipStream_t stream) {
    const float* x     = (const float*)d_in[0];
    const int*   ei    = (const int*)d_in[1];
    const int*   batch = (const int*)d_in[2];
    const float* Wl    = (const float*)d_in[3];
    const float* bl    = (const float*)d_in[4];
    const float* Wr    = (const float*)d_in[5];
    const float* bng   = (const float*)d_in[6];
    const float* bnb   = (const float*)d_in[7];
    const float* bn2g  = (const float*)d_in[8];
    const float* bn2b  = (const float*)d_in[9];
    const float* fcW   = (const float*)d_in[10];
    const float* fcb   = (const float*)d_in[11];

    int N = in_sizes[0] / HD;
    int E = in_sizes[1] / 2;
    int G = out_size / 64;
    const int* src = ei;
    const int* dst = ei + E;

    char* p = (char*)d_ws;
    auto alloc = [&](size_t bytes) -> void* {
        void* r = (void*)p;
        p += (bytes + 255) & ~(size_t)255;
        return r;
    };
    int NB = (N + BSZ - 1) >> BSH;
    int nPB = (E + EPB - 1) / EPB;

    int*    rowptr   = (int*)alloc((size_t)(N + 1) * 4);
    int*    csr      = (int*)alloc((size_t)E * 4);
    float*  inv      = (float*)alloc((size_t)N * 4);
    ushort* WTS      = (ushort*)alloc((size_t)3 * 128 * 256 * 2);
    ushort* xb       = (ushort*)alloc((size_t)N * HD * 2);
    ushort* aggb     = (ushort*)alloc((size_t)N * HD * 2);
    ushort* hb1      = (ushort*)alloc((size_t)N * HD * 2);
    ushort* hb2      = (ushort*)alloc((size_t)N * HD * 2);
    char*   zbase    = (char*)alloc(0);
    float*  statsAll = (float*)alloc((size_t)4 * NCOPY * 256 * 4);
    float*  pooled   = (float*)alloc((size_t)G * HD * 4);
    int*    bCount   = (int*)alloc((size_t)NB * 4);
    int*    gCursor  = (int*)alloc((size_t)NB * 4);
    size_t  zbytes   = (size_t)((char*)p - zbase);

    float* stats0  = statsAll;
    float* stats1  = statsAll + NCOPY * 256;
    float* statsL2 = statsAll + 2 * NCOPY * 256;
    float* stats2  = statsAll + 3 * NCOPY * 256;

    // packed edge list overlays aggb: dead before first k_agg writes aggb (stream-ordered)
    unsigned int* packed = (unsigned int*)aggb;

    float* outp = (float*)d_out;
    int total4 = N * HD / 4;
    int total8 = N * HD / 8;
    int ggrid = (N + 127) / 128;
    int agrid = (N + 3) / 4;
    float fN = (float)N, fG = (float)G;

    hipMemsetAsync(zbase, 0, zbytes, stream);
    k_prepcount<<<nPB + 1024, 256, 0, stream>>>(x, xb, total4, Wl, Wr, WTS, 3 * 128 * 256,
                                                dst, bCount, E, NB, nPB);
    kp_part<<<nPB, 256, 0, stream>>>(src, dst, bCount, gCursor, packed, E, NB);
    kp_degfill<<<NB, 256, 0, stream>>>(packed, bCount, rowptr, inv, csr, N, E, NB);

    // layer 0: h=xb -> hb1
    k_agg<<<agrid, 256, 0, stream>>>(xb, rowptr, csr, inv, aggb, N);
    k_gemm<<<ggrid, 256, 0, stream>>>(aggb, xb, WTS, bl, hb1, stats0, N);
    k_apply<<<2048, 256, 0, stream>>>(hb1, stats0, bng, bnb, fN, total8);

    // layer 1: h=hb1 -> hb2
    k_agg<<<agrid, 256, 0, stream>>>(hb1, rowptr, csr, inv, aggb, N);
    k_gemm<<<ggrid, 256, 0, stream>>>(aggb, hb1, WTS + 32768, bl + 128, hb2, stats1, N);
    k_apply<<<2048, 256, 0, stream>>>(hb2, stats1, bng + 128, bnb + 128, fN, total8);

    // layer 2: h=hb2 -> hb1 (pre-BN); BN finalize+apply fused into pooling
    k_agg<<<agrid, 256, 0, stream>>>(hb2, rowptr, csr, inv, aggb, N);
    k_gemm<<<ggrid, 256, 0, stream>>>(aggb, hb2, WTS + 65536, bl + 256, hb1, statsL2, N);
    k_poolapply<<<(N + 63) / 64, HD, 0, stream>>>(hb1, statsL2, bng + 256, bnb + 256, fN,
                                                  batch, pooled, N);

    // final BN + FC
    k_colstats<<<64, HD, 0, stream>>>(pooled, stats2, G);
    k_final<<<G, HD, 0, stream>>>(pooled, stats2, bn2g, bn2b, fcW, fcb, outp, fG);
}

// Round 12
// 377.999 us; speedup vs baseline: 1.2941x; 1.0093x over previous
//
#include <hip/hip_runtime.h>

#define HD 128
#define NCOPY 32
#define BSH 8
#define BSZ 256
#define EPB 4096

typedef __attribute__((ext_vector_type(8))) short short8;
typedef __attribute__((ext_vector_type(4))) float f32x4;

union ABu { unsigned long long u[2]; short8 s8; };

typedef const __attribute__((address_space(1))) void* gas_t;
typedef __attribute__((address_space(3))) void* las_t;

__device__ inline float bf2f(ushort u) {
    union { unsigned int i; float f; } x; x.i = ((unsigned int)u) << 16; return x.f;
}
__device__ inline float bflo(unsigned int u) {
    union { unsigned int i; float f; } x; x.i = u << 16; return x.f;
}
__device__ inline float bfhi(unsigned int u) {
    union { unsigned int i; float f; } x; x.i = u & 0xffff0000u; return x.f;
}
__device__ inline ushort f2bf(float f) {
    union { float f; unsigned int i; } x; x.f = f;
    unsigned int r = x.i + 0x7FFF + ((x.i >> 16) & 1);
    return (ushort)(r >> 16);
}

// XOR-swizzled fragment read from linear [*][64-ushort] tile (rows 128B apart).
// LDS[row][sb] holds global block (sb ^ (row&7)); reading block b uses sb = b ^ (row&7).
__device__ inline short8 frag_read(const ushort* tile, int row, int kk, int kg) {
    const char* rowp = (const char*)(tile + row * 64);
    int sw = (row & 7) << 4;
    int b0 = kk * 64 + kg * 8;
    int a0 = (b0 & 15) | ((b0 & ~15) ^ sw);
    int b1 = b0 + 32;
    int a1 = (b1 & 15) | ((b1 & ~15) ^ sw);
    ABu u;
    u.u[0] = *(const unsigned long long*)(rowp + a0);
    u.u[1] = *(const unsigned long long*)(rowp + a1);
    return u.s8;
}

// ---------------- prep (x->bf16, WTS frag-major->bf16, zero stats/pooled) + count ------
// WTS frag-major (per layer, 32768 ushorts): idx = ((c*2+kk)*128 + col)*32 + kg*8 + e,
// element = W[k][col], k = c*64 + kk*32 + kg*4 + (e&3) + ((e>>2)<<4); k<128 -> Wl else Wr.
__global__ __launch_bounds__(256) void k_prepcount(
        const float* __restrict__ x, ushort* __restrict__ xb, int total4,
        const float* __restrict__ Wl, const float* __restrict__ Wr,
        ushort* __restrict__ WTS, int wtTotal,
        float* __restrict__ zbuf, int ztotal4,
        const int* __restrict__ dst, int* __restrict__ bucketCount, int E, int NB, int nPB) {
    __shared__ int hist[512];
    if (blockIdx.x < nPB) {
        for (int i = threadIdx.x; i < NB; i += 256) hist[i] = 0;
        __syncthreads();
        int e0 = blockIdx.x * EPB;
#pragma unroll
        for (int j = 0; j < 16; ++j) {
            int e = e0 + j * 256 + threadIdx.x;
            if (e < E) atomicAdd(&hist[dst[e] >> BSH], 1);
        }
        __syncthreads();
        for (int i = threadIdx.x; i < NB; i += 256)
            if (hist[i]) atomicAdd(&bucketCount[i], hist[i]);
    } else {
        int i = (blockIdx.x - nPB) * 256 + threadIdx.x;
        int stride = (gridDim.x - nPB) * 256;
        for (int idx = i; idx < total4; idx += stride) {
            float4 v = ((const float4*)x)[idx];
            ushort4 o;
            o.x = f2bf(v.x); o.y = f2bf(v.y); o.z = f2bf(v.z); o.w = f2bf(v.w);
            ((ushort4*)xb)[idx] = o;
        }
        for (int idx = i; idx < wtTotal; idx += stride) {
            int l = idx >> 15;
            int r = idx & 32767;
            int ckk = r >> 12;
            int c = ckk >> 1, kk = ckk & 1;
            int r2 = r & 4095;
            int col = r2 >> 5;
            int r3 = r2 & 31;
            int kg = r3 >> 3, e = r3 & 7;
            int k = c * 64 + kk * 32 + kg * 4 + (e & 3) + ((e >> 2) << 4);
            float v = (k < 128) ? Wl[l * 16384 + k * 128 + col]
                                : Wr[l * 16384 + (k - 128) * 128 + col];
            WTS[idx] = f2bf(v);
        }
        float4 z = make_float4(0.f, 0.f, 0.f, 0.f);
        for (int idx = i; idx < ztotal4; idx += stride) ((float4*)zbuf)[idx] = z;
    }
}

// ---------------- partition: computes bucket bases internally (scan of bCount) ---------
__global__ __launch_bounds__(256) void kp_part(const int* __restrict__ src,
                                               const int* __restrict__ dst,
                                               const int* __restrict__ bCount,
                                               int* __restrict__ gCursor,
                                               unsigned int* __restrict__ packed,
                                               int E, int NB) {
    __shared__ int bbase[512];
    __shared__ int pair[256];
    __shared__ int hist[512], lbase[512], lcur[512];
    int tid = threadIdx.x;
    int i0 = 2 * tid, i1 = 2 * tid + 1;
    int v0 = (i0 < NB) ? bCount[i0] : 0;
    int v1 = (i1 < NB) ? bCount[i1] : 0;
    pair[tid] = v0 + v1;
    __syncthreads();
    for (int off = 1; off < 256; off <<= 1) {
        int t = 0;
        if (tid >= off) t = pair[tid - off];
        __syncthreads();
        if (tid >= off) pair[tid] += t;
        __syncthreads();
    }
    int incl = pair[tid];
    bbase[i0] = incl - v0 - v1;
    bbase[i1] = incl - v1;
    for (int i = tid; i < NB; i += 256) hist[i] = 0;
    __syncthreads();

    int e0 = blockIdx.x * EPB;
    int b[16]; unsigned int w[16];
#pragma unroll
    for (int j = 0; j < 16; ++j) {
        int e = e0 + j * 256 + tid;
        b[j] = -1;
        if (e < E) {
            int d = dst[e];
            int s = src[e];
            b[j] = d >> BSH;
            w[j] = (unsigned int)s | (((unsigned int)d & (BSZ - 1)) << 17);
            atomicAdd(&hist[b[j]], 1);
        }
    }
    __syncthreads();
    for (int i = tid; i < NB; i += 256) {
        int c = hist[i];
        lbase[i] = c ? (bbase[i] + atomicAdd(&gCursor[i], c)) : 0;
        lcur[i] = 0;
    }
    __syncthreads();
#pragma unroll
    for (int j = 0; j < 16; ++j) {
        if (b[j] >= 0) {
            int r = atomicAdd(&lcur[b[j]], 1);
            packed[lbase[b[j]] + r] = w[j];
        }
    }
}

// ---------------- degfill: bucket base via internal reduction; rowptr/inv/csr ----------
__global__ __launch_bounds__(256) void kp_degfill(const unsigned int* __restrict__ packed,
                                                  const int* __restrict__ bCount,
                                                  int* __restrict__ rowptr,
                                                  float* __restrict__ inv,
                                                  int* __restrict__ csr, int N, int E, int NB) {
    __shared__ int dcnt[BSZ];
    __shared__ int scn[BSZ];
    __shared__ int rp[BSZ];
    __shared__ int red[256];
    int bkt = blockIdx.x;
    int tid = threadIdx.x;
    int n0 = bkt << BSH;
    int partial = 0;
    for (int i = tid; i < bkt; i += 256) partial += bCount[i];
    red[tid] = partial;
    __syncthreads();
    for (int off = 128; off > 0; off >>= 1) {
        if (tid < off) red[tid] += red[tid + off];
        __syncthreads();
    }
    int beg = red[0];
    int end = beg + bCount[bkt];
    __syncthreads();
    dcnt[tid] = 0;
    __syncthreads();
    for (int e = beg + tid; e < end; e += 256)
        atomicAdd(&dcnt[packed[e] >> 17], 1);
    __syncthreads();
    int v = dcnt[tid];
    scn[tid] = v;
    __syncthreads();
    for (int off = 1; off < 256; off <<= 1) {
        int t = 0;
        if (tid >= off) t = scn[tid - off];
        __syncthreads();
        if (tid >= off) scn[tid] += t;
        __syncthreads();
    }
    int rpv = beg + scn[tid] - v;
    int n = n0 + tid;
    if (n < N) {
        rowptr[n] = rpv;
        inv[n] = (v > 0) ? (1.0f / (float)v) : 0.0f;
    }
    if (bkt == 0 && tid == 0) rowptr[N] = E;
    __syncthreads();
    dcnt[tid] = 0;
    rp[tid] = rpv;
    __syncthreads();
    for (int e = beg + tid; e < end; e += 256) {
        unsigned int wv = packed[e];
        int ld = wv >> 17;
        int p = atomicAdd(&dcnt[ld], 1);
        csr[rp[ld] + p] = (int)(wv & 0x1FFFF);
    }
}

// ---------------- Aggregation: one wave per node, 8 rows in flight (R5-proven) ----------------
__global__ __launch_bounds__(256) void k_agg(const ushort* __restrict__ h,
                                             const int* __restrict__ rowptr,
                                             const int* __restrict__ csr,
                                             const float* __restrict__ inv,
                                             ushort* __restrict__ agg, int N) {
    int node = blockIdx.x * 4 + (threadIdx.x >> 6);
    if (node >= N) return;
    int lane = threadIdx.x & 63;
    int g = lane >> 4, ln = lane & 15;
    int beg = rowptr[node], end = rowptr[node + 1];
    float a[8], b[8];
#pragma unroll
    for (int j = 0; j < 8; ++j) { a[j] = 0.f; b[j] = 0.f; }
    for (int e = beg + g; e < end; e += 8) {
        int s0 = csr[e];
        uint4 v0 = *(const uint4*)&h[(size_t)s0 * HD + ln * 8];
        int e1 = e + 4;
        if (e1 < end) {
            int s1 = csr[e1];
            uint4 v1 = *(const uint4*)&h[(size_t)s1 * HD + ln * 8];
            b[0] += bflo(v1.x); b[1] += bfhi(v1.x);
            b[2] += bflo(v1.y); b[3] += bfhi(v1.y);
            b[4] += bflo(v1.z); b[5] += bfhi(v1.z);
            b[6] += bflo(v1.w); b[7] += bfhi(v1.w);
        }
        a[0] += bflo(v0.x); a[1] += bfhi(v0.x);
        a[2] += bflo(v0.y); a[3] += bfhi(v0.y);
        a[4] += bflo(v0.z); a[5] += bfhi(v0.z);
        a[6] += bflo(v0.w); a[7] += bfhi(v0.w);
    }
#pragma unroll
    for (int j = 0; j < 8; ++j) {
        a[j] += b[j];
        a[j] += __shfl_xor(a[j], 16);
        a[j] += __shfl_xor(a[j], 32);
    }
    if (lane < 16) {
        float iv = inv[node];
        ushort o[8];
#pragma unroll
        for (int j = 0; j < 8; ++j) o[j] = f2bf(a[j] * iv);
        *(uint4*)&agg[(size_t)node * HD + ln * 8] = *(uint4*)o;
    }
}

// ---------------- MFMA dual-GEMM: A via global_load_lds (swizzled), B direct from L2 ----
// 128x128 tile, 4 waves (2x2), K=256 in 4 chunks of 64 (chunks 0-1: X1@Wl; 2-3: X2@Wr).
// B fragments loaded straight from frag-major WTS (L2-hot) into regs - no LDS staging.
__global__ __launch_bounds__(256) void k_gemm(
        const ushort* __restrict__ X1, const ushort* __restrict__ X2,
        const ushort* __restrict__ WTS, const float* __restrict__ bias,
        ushort* __restrict__ out, float* __restrict__ stats, int N) {
    __shared__ ushort As[128 * 64];   // 16 KB
    int tid = threadIdx.x;
    int lane = tid & 63, wid = tid >> 6;
    int wr = wid >> 1, wc = wid & 1;
    int ln15 = lane & 15, kg = lane >> 4;
    int rbase = blockIdx.x * 128;
    int lrow = lane >> 3;     // 0..7 within instruction
    int sb = lane & 7;        // block 0..7

    f32x4 acc[4][4];
#pragma unroll
    for (int m = 0; m < 4; ++m)
#pragma unroll
        for (int nn = 0; nn < 4; ++nn) acc[m][nn] = (f32x4){0.f, 0.f, 0.f, 0.f};

    for (int c = 0; c < 4; ++c) {
        const ushort* X = (c < 2) ? X1 : X2;
        size_t cbyte = (size_t)(c & 1) * 128;   // byte offset within X row
#pragma unroll
        for (int p = 0; p < 4; ++p) {
            int instr = wid * 4 + p;                 // 0..15
            int row_local = instr * 8 + lrow;
            int grow = rbase + row_local;
            if (grow >= N) grow = N - 1;             // rows >= N never stored
            const char* gpA = (const char*)X + (size_t)grow * 256 + cbyte
                              + ((sb ^ (row_local & 7)) << 4);
            __builtin_amdgcn_global_load_lds((gas_t)gpA,
                    (las_t)((char*)As + instr * 1024), 16, 0, 0);
        }
        // B fragments direct from L2 (frag-major layout, 16B/lane coalesced)
        short8 bfr[2][4];
#pragma unroll
        for (int kk = 0; kk < 2; ++kk)
#pragma unroll
            for (int nn = 0; nn < 4; ++nn) {
                int col = wc * 64 + nn * 16 + ln15;
                bfr[kk][nn] = *(const short8*)&WTS[((size_t)(c * 2 + kk) * 128 + col) * 32 + kg * 8];
            }
        __syncthreads();
#pragma unroll
        for (int kk = 0; kk < 2; ++kk) {
            short8 af[4];
#pragma unroll
            for (int m = 0; m < 4; ++m)
                af[m] = frag_read(As, wr * 64 + m * 16 + ln15, kk, kg);
#pragma unroll
            for (int m = 0; m < 4; ++m)
#pragma unroll
                for (int nn = 0; nn < 4; ++nn)
                    acc[m][nn] = __builtin_amdgcn_mfma_f32_16x16x32_bf16(af[m], bfr[kk][nn], acc[m][nn], 0, 0, 0);
        }
        __syncthreads();
    }

    float s[4] = {0.f, 0.f, 0.f, 0.f};
    float q[4] = {0.f, 0.f, 0.f, 0.f};
    float bv[4];
#pragma unroll
    for (int nn = 0; nn < 4; ++nn) bv[nn] = bias[wc * 64 + nn * 16 + ln15];
#pragma unroll
    for (int m = 0; m < 4; ++m) {
#pragma unroll
        for (int j = 0; j < 4; ++j) {
            int row = rbase + wr * 64 + m * 16 + kg * 4 + j;
            if (row < N) {
#pragma unroll
                for (int nn = 0; nn < 4; ++nn) {
                    float v = acc[m][nn][j] + bv[nn];
                    out[(size_t)row * HD + wc * 64 + nn * 16 + ln15] = f2bf(v);
                    s[nn] += v; q[nn] += v * v;
                }
            }
        }
    }
#pragma unroll
    for (int nn = 0; nn < 4; ++nn) {
        s[nn] += __shfl_xor(s[nn], 16); s[nn] += __shfl_xor(s[nn], 32);
        q[nn] += __shfl_xor(q[nn], 16); q[nn] += __shfl_xor(q[nn], 32);
    }
    if (lane < 16) {
        int slot = (blockIdx.x & (NCOPY - 1)) * 256;
#pragma unroll
        for (int nn = 0; nn < 4; ++nn) {
            int col = wc * 64 + nn * 16 + lane;
            atomicAdd(&stats[slot + col], s[nn]);
            atomicAdd(&stats[slot + 128 + col], q[nn]);
        }
    }
}

// ---------------- BN finalize folded + apply + LeakyReLU, IN-PLACE ----------------
__global__ __launch_bounds__(256) void k_apply(ushort* buf, const float* __restrict__ stats,
                                               const float* __restrict__ gamma,
                                               const float* __restrict__ beta,
                                               float count, int total8) {
    __shared__ float sc[HD], sh[HD];
    int tid = threadIdx.x;
    if (tid < HD) {
        float s = 0.f, q = 0.f;
        for (int i = 0; i < NCOPY; ++i) { s += stats[i * 256 + tid]; q += stats[i * 256 + 128 + tid]; }
        float mean = s / count;
        float var = fmaxf(q / count - mean * mean, 0.f);
        float scale = gamma[tid] * rsqrtf(var + 1e-5f);
        sc[tid] = scale;
        sh[tid] = beta[tid] - mean * scale;
    }
    __syncthreads();
    int i = blockIdx.x * blockDim.x + tid;
    int stride = gridDim.x * blockDim.x;
    for (int idx = i; idx < total8; idx += stride) {
        int cb = (idx * 8) & (HD - 1);
        uint4 v = ((const uint4*)buf)[idx];
        float f[8];
        f[0] = bflo(v.x); f[1] = bfhi(v.x);
        f[2] = bflo(v.y); f[3] = bfhi(v.y);
        f[4] = bflo(v.z); f[5] = bfhi(v.z);
        f[6] = bflo(v.w); f[7] = bfhi(v.w);
        ushort o[8];
#pragma unroll
        for (int j = 0; j < 8; ++j) {
            float y = f[j] * sc[cb + j] + sh[cb + j];
            y = (y > 0.f) ? y : 0.2f * y;
            o[j] = f2bf(y);
        }
        ((uint4*)buf)[idx] = *(uint4*)o;
    }
}

// ---------------- Pooling, 64 nodes/block, fused BN finalize+apply ----------------
__global__ void k_poolapply(const ushort* __restrict__ h, const float* __restrict__ stats,
                            const float* __restrict__ gamma, const float* __restrict__ beta,
                            float count, const int* __restrict__ batch,
                            float* __restrict__ pooled, int N) {
    int c = threadIdx.x;  // 128
    float s = 0.f, q = 0.f;
    for (int i = 0; i < NCOPY; ++i) { s += stats[i * 256 + c]; q += stats[i * 256 + 128 + c]; }
    float mean = s / count;
    float var = fmaxf(q / count - mean * mean, 0.f);
    float sc = gamma[c] * rsqrtf(var + 1e-5f);
    float sh = beta[c] - mean * sc;
    int n0 = blockIdx.x * 64;
    if (n0 >= N) return;
    int nend = min(n0 + 64, N);
    float acc = 0.f;
    int cur = batch[n0];
    for (int n = n0; n < nend; ++n) {
        int b = batch[n];
        if (b != cur) { atomicAdd(&pooled[cur * HD + c], acc); acc = 0.f; cur = b; }
        float y = bf2f(h[(size_t)n * HD + c]) * sc + sh;
        y = (y > 0.f) ? y : 0.2f * y;
        acc += y;
    }
    atomicAdd(&pooled[cur * HD + c], acc);
}

// ---------------- column stats over pooled [rows][128] ----------------
__global__ void k_colstats(const float* __restrict__ X, float* __restrict__ stats, int rows) {
    int c = threadIdx.x;  // 128
    float s = 0.f, q = 0.f;
    for (int r = blockIdx.x; r < rows; r += gridDim.x) {
        float v = X[r * HD + c];
        s += v; q += v * v;
    }
    int slot = (blockIdx.x & (NCOPY - 1)) * 256;
    atomicAdd(&stats[slot + c], s);
    atomicAdd(&stats[slot + 128 + c], q);
}

// ---------------- final: BN2 finalize folded; out[g] = bn2(pooled[g]) @ fcW + fcb ------
__global__ void k_final(const float* __restrict__ pooled, const float* __restrict__ stats2,
                        const float* __restrict__ bn2g, const float* __restrict__ bn2b,
                        const float* __restrict__ fcW, const float* __restrict__ fcb,
                        float* __restrict__ outp, float countG) {
    __shared__ float Wlds[HD * 64];
    __shared__ float prow[HD];
    int tid = threadIdx.x;  // 128
    for (int i = tid; i < HD * 64 / 4; i += 128) ((float4*)Wlds)[i] = ((const float4*)fcW)[i];
    float s = 0.f, q = 0.f;
    for (int i = 0; i < NCOPY; ++i) { s += stats2[i * 256 + tid]; q += stats2[i * 256 + 128 + tid]; }
    float mean = s / countG;
    float var = fmaxf(q / countG - mean * mean, 0.f);
    float scale = bn2g[tid] * rsqrtf(var + 1e-5f);
    float shift = bn2b[tid] - mean * scale;
    int g = blockIdx.x;
    prow[tid] = pooled[g * HD + tid] * scale + shift;
    __syncthreads();
    if (tid < 64) {
        float acc = fcb[tid];
#pragma unroll 8
        for (int c = 0; c < HD; ++c) acc += prow[c] * Wlds[c * 64 + tid];
        outp[g * 64 + tid] = acc;
    }
}

// ---------------- host orchestration ----------------
extern "C" void kernel_launch(void* const* d_in, const int* in_sizes, int n_in,
                              void* d_out, int out_size, void* d_ws, size_t ws_size,
                              hipStream_t stream) {
    const float* x     = (const float*)d_in[0];
    const int*   ei    = (const int*)d_in[1];
    const int*   batch = (const int*)d_in[2];
    const float* Wl    = (const float*)d_in[3];
    const float* bl    = (const float*)d_in[4];
    const float* Wr    = (const float*)d_in[5];
    const float* bng   = (const float*)d_in[6];
    const float* bnb   = (const float*)d_in[7];
    const float* bn2g  = (const float*)d_in[8];
    const float* bn2b  = (const float*)d_in[9];
    const float* fcW   = (const float*)d_in[10];
    const float* fcb   = (const float*)d_in[11];

    int N = in_sizes[0] / HD;
    int E = in_sizes[1] / 2;
    int G = out_size / 64;
    const int* src = ei;
    const int* dst = ei + E;

    char* p = (char*)d_ws;
    auto alloc = [&](size_t bytes) -> void* {
        void* r = (void*)p;
        p += (bytes + 255) & ~(size_t)255;
        return r;
    };
    int NB = (N + BSZ - 1) >> BSH;
    int nPB = (E + EPB - 1) / EPB;

    int*    rowptr   = (int*)alloc((size_t)(N + 1) * 4);
    int*    csr      = (int*)alloc((size_t)E * 4);
    float*  inv      = (float*)alloc((size_t)N * 4);
    ushort* WTS      = (ushort*)alloc((size_t)3 * 128 * 256 * 2);
    ushort* xb       = (ushort*)alloc((size_t)N * HD * 2);
    ushort* aggb     = (ushort*)alloc((size_t)N * HD * 2);
    ushort* hb1      = (ushort*)alloc((size_t)N * HD * 2);
    ushort* hb2      = (ushort*)alloc((size_t)N * HD * 2);
    // stats (4 sets) + pooled contiguous: zeroed inside k_prepcount
    float*  statsAll = (float*)alloc((size_t)4 * NCOPY * 256 * 4);
    float*  pooled   = (float*)alloc((size_t)G * HD * 4);
    // small memset region: bCount + gCursor
    char*   zbase    = (char*)alloc(0);
    int*    bCount   = (int*)alloc((size_t)NB * 4);
    int*    gCursor  = (int*)alloc((size_t)NB * 4);
    size_t  zbytes   = (size_t)((char*)p - zbase);

    float* stats0  = statsAll;
    float* stats1  = statsAll + NCOPY * 256;
    float* statsL2 = statsAll + 2 * NCOPY * 256;
    float* stats2  = statsAll + 3 * NCOPY * 256;
    int ztotal4 = (4 * NCOPY * 256 * 4 + G * HD * 4) / 16;   // float4 count (contiguous)

    // packed edge list overlays aggb: dead before first k_agg writes aggb (stream-ordered)
    unsigned int* packed = (unsigned int*)aggb;

    float* outp = (float*)d_out;
    int total4 = N * HD / 4;
    int total8 = N * HD / 8;
    int ggrid = (N + 127) / 128;
    int agrid = (N + 3) / 4;
    float fN = (float)N, fG = (float)G;

    hipMemsetAsync(zbase, 0, zbytes, stream);
    k_prepcount<<<nPB + 1024, 256, 0, stream>>>(x, xb, total4, Wl, Wr, WTS, 3 * 128 * 256,
                                                statsAll, ztotal4,
                                                dst, bCount, E, NB, nPB);
    kp_part<<<nPB, 256, 0, stream>>>(src, dst, bCount, gCursor, packed, E, NB);
    kp_degfill<<<NB, 256, 0, stream>>>(packed, bCount, rowptr, inv, csr, N, E, NB);

    // layer 0: h=xb -> hb1
    k_agg<<<agrid, 256, 0, stream>>>(xb, rowptr, csr, inv, aggb, N);
    k_gemm<<<ggrid, 256, 0, stream>>>(aggb, xb, WTS, bl, hb1, stats0, N);
    k_apply<<<2048, 256, 0, stream>>>(hb1, stats0, bng, bnb, fN, total8);

    // layer 1: h=hb1 -> hb2
    k_agg<<<agrid, 256, 0, stream>>>(hb1, rowptr, csr, inv, aggb, N);
    k_gemm<<<ggrid, 256, 0, stream>>>(aggb, hb1, WTS + 32768, bl + 128, hb2, stats1, N);
    k_apply<<<2048, 256, 0, stream>>>(hb2, stats1, bng + 128, bnb + 128, fN, total8);

    // layer 2: h=hb2 -> hb1 (pre-BN); BN finalize+apply fused into pooling
    k_agg<<<agrid, 256, 0, stream>>>(hb2, rowptr, csr, inv, aggb, N);
    k_gemm<<<ggrid, 256, 0, stream>>>(aggb, hb2, WTS + 65536, bl + 256, hb1, statsL2, N);
    k_poolapply<<<(N + 63) / 64, HD, 0, stream>>>(hb1, statsL2, bng + 256, bnb + 256, fN,
                                                  batch, pooled, N);

    // final BN + FC
    k_colstats<<<64, HD, 0, stream>>>(pooled, stats2, G);
    k_final<<<G, HD, 0, stream>>>(pooled, stats2, bn2g, bn2b, fcW, fcb, outp, fG);
}